// Round 2
// baseline (165.371 us; speedup 1.0000x reference)
//
#include <hip/hip_runtime.h>

typedef __attribute__((ext_vector_type(8))) _Float16 f16x8;
typedef __attribute__((ext_vector_type(4))) float f32x4;

__device__ __forceinline__ f16x8 cvt8(f32x4 a, f32x4 b) {
  f16x8 h;
  h[0] = (_Float16)a.x; h[1] = (_Float16)a.y; h[2] = (_Float16)a.z; h[3] = (_Float16)a.w;
  h[4] = (_Float16)b.x; h[5] = (_Float16)b.y; h[6] = (_Float16)b.z; h[7] = (_Float16)b.w;
  return h;
}

__device__ __forceinline__ float dot4(f32x4 a, f32x4 b) {
  return a.x * b.x + a.y * b.y + a.z * b.z + a.w * b.w;
}

// Block = 16 batch elements. Wave w owns output-feature tile [16w,16w+16).
// M-dim = batch (16), B-operand = W rows for this wave's tile.
// Inter-layer exchange (all 64 input feats needed) via small LDS tile + barriers.
__global__ __launch_bounds__(256, 6) void gcn_fused(
    const float* __restrict__ x,
    const float* __restrict__ W1, const float* __restrict__ B1,
    const float* __restrict__ W2, const float* __restrict__ B2,
    const float* __restrict__ W3, const float* __restrict__ B3,
    const float* __restrict__ W4, const float* __restrict__ B4,
    const float* __restrict__ fcw, const float* __restrict__ fcb,
    float* __restrict__ out)
{
  __shared__ __align__(16) _Float16 xs[6][16][72];  // h[node][batch][feat], 144B rows spread banks
  __shared__ float ps[4][6][16];                    // per-wave epilogue partial dots
  __shared__ float pacc_s[6][16];                   // residual x . fc_w partials

  const int tid  = threadIdx.x;
  const int lane = tid & 63;
  const int w    = tid >> 6;     // wave id = output-feature tile
  const int c    = lane & 15;    // A-row (batch) / B-col (feature) / C-col
  const int q    = lane >> 4;    // k-group / C row-group
  const int b0   = blockIdx.x * 16;

  const int NB0[6] = {1, 0, 1, 2, 3, 3};
  const int NB1[6] = {2, 2, 3, 4, 5, 4};
  const float* Ws[4] = {W1, W2, W3, W4};
  const float* Bs[4] = {B1, B2, B3, B4};

  const f32x4 z4 = {0.f, 0.f, 0.f, 0.f};
  f32x4 acc[6];
  float pacc[6] = {0.f, 0.f, 0.f, 0.f, 0.f, 0.f};

  auto aggregate = [&](float ca, float cb, float bv) {
    f32x4 t[6];
#pragma unroll
    for (int n = 0; n < 6; ++n) {
      f32x4 s = acc[NB0[n]] + acc[NB1[n]];
#pragma unroll
      for (int e = 0; e < 4; ++e)
        t[n][e] = fmaxf(0.f, ca * acc[n][e] + cb * s[e] + bv);
    }
#pragma unroll
    for (int n = 0; n < 6; ++n) acc[n] = t[n];
  };

  // ---------------- layer 1: x from global, fold residual fc-dot ----------------
  {
    const float* wp = W1 + (w * 16 + c) * 64 + q * 8;
    const f16x8 wf0 = cvt8(*(const f32x4*)wp,        *(const f32x4*)(wp + 4));
    const f16x8 wf1 = cvt8(*(const f32x4*)(wp + 32), *(const f32x4*)(wp + 36));
#pragma unroll
    for (int n = 0; n < 6; ++n) {
      const float* src = x + (((size_t)(b0 + c) * 6 + n) * 64 + q * 8);
      f32x4 v0 = *(const f32x4*)src;
      f32x4 v1 = *(const f32x4*)(src + 4);
      f32x4 v2 = *(const f32x4*)(src + 32);
      f32x4 v3 = *(const f32x4*)(src + 36);
      if (w == 0) {  // wave-uniform: only wave 0 computes the residual partials
        const float* fw = fcw + n * 64 + q * 8;
        float p = dot4(v0, *(const f32x4*)fw) + dot4(v1, *(const f32x4*)(fw + 4))
                + dot4(v2, *(const f32x4*)(fw + 32)) + dot4(v3, *(const f32x4*)(fw + 36));
        p += __shfl_xor(p, 16, 64);
        p += __shfl_xor(p, 32, 64);
        pacc[n] = p;  // full dot(x[b0+c,n,:], fcw[n,:]) at batch c
      }
      f16x8 a0 = cvt8(v0, v1), a1 = cvt8(v2, v3);
      f32x4 d = __builtin_amdgcn_mfma_f32_16x16x32_f16(a0, wf0, z4, 0, 0, 0);
      acc[n]  = __builtin_amdgcn_mfma_f32_16x16x32_f16(a1, wf1, d, 0, 0, 0);
    }
    aggregate(1.f / 3.f, 1.f / 3.f, B1[w * 16 + c]);
  }
  // store h1 (C-frag: col = w*16+c feature, rows q*4+e batch -> xs[n][b][g])
#pragma unroll
  for (int n = 0; n < 6; ++n)
#pragma unroll
    for (int e = 0; e < 4; ++e)
      xs[n][q * 4 + e][w * 16 + c] = (_Float16)acc[n][e];

  // ---------------- layers 2..4 ----------------
#pragma unroll
  for (int l = 1; l < 4; ++l) {
    const float* wp = Ws[l] + (w * 16 + c) * 64 + q * 8;
    const f16x8 wf0 = cvt8(*(const f32x4*)wp,        *(const f32x4*)(wp + 4));
    const f16x8 wf1 = cvt8(*(const f32x4*)(wp + 32), *(const f32x4*)(wp + 36));
    const float bv = Bs[l][w * 16 + c];
    __syncthreads();  // previous layer's xs writes visible
#pragma unroll
    for (int n = 0; n < 6; ++n) {
      f16x8 a0 = *(const f16x8*)&xs[n][c][q * 8];
      f16x8 a1 = *(const f16x8*)&xs[n][c][q * 8 + 32];
      f32x4 d = __builtin_amdgcn_mfma_f32_16x16x32_f16(a0, wf0, z4, 0, 0, 0);
      acc[n]  = __builtin_amdgcn_mfma_f32_16x16x32_f16(a1, wf1, d, 0, 0, 0);
    }
    aggregate(l < 2 ? (1.f / 3.f) : 0.5f, l < 2 ? (1.f / 3.f) : 0.25f, bv);
    if (l < 3) {
      __syncthreads();  // all waves done reading h_l before overwrite
#pragma unroll
      for (int n = 0; n < 6; ++n)
#pragma unroll
        for (int e = 0; e < 4; ++e)
          xs[n][q * 4 + e][w * 16 + c] = (_Float16)acc[n][e];
    }
  }

  // ---------------- epilogue: per-wave partial dot over its 16 features ----------------
#pragma unroll
  for (int n = 0; n < 6; ++n) {
    const float fwv = fcw[n * 64 + w * 16 + c];
    f32x4 sv = acc[n] * fwv;
#pragma unroll
    for (int m = 1; m <= 8; m <<= 1) {  // reduce over c (feature cols of this tile)
      sv.x += __shfl_xor(sv.x, m, 64);
      sv.y += __shfl_xor(sv.y, m, 64);
      sv.z += __shfl_xor(sv.z, m, 64);
      sv.w += __shfl_xor(sv.w, m, 64);
    }
    if (c == 0) {
      ps[w][n][q * 4 + 0] = sv.x;
      ps[w][n][q * 4 + 1] = sv.y;
      ps[w][n][q * 4 + 2] = sv.z;
      ps[w][n][q * 4 + 3] = sv.w;
    }
  }
  if (w == 0 && q == 0) {
#pragma unroll
    for (int n = 0; n < 6; ++n) pacc_s[n][c] = pacc[n];
  }
  __syncthreads();

  // combine 4 wave-slices + residual + bias, sigmoid, one coalesced 384B store
  if (tid < 96) {
    const int b = tid / 6;
    const int n = tid - b * 6;
    float v = ps[0][n][b] + ps[1][n][b] + ps[2][n][b] + ps[3][n][b]
            + pacc_s[n][b] + fcb[n];
    out[(size_t)b0 * 6 + tid] = 1.f / (1.f + __expf(-v));
  }
}

extern "C" void kernel_launch(void* const* d_in, const int* in_sizes, int n_in,
                              void* d_out, int out_size, void* d_ws, size_t ws_size,
                              hipStream_t stream) {
  const float* x   = (const float*)d_in[0];
  const float* W1  = (const float*)d_in[1];
  const float* B1  = (const float*)d_in[2];
  const float* W2  = (const float*)d_in[3];
  const float* B2  = (const float*)d_in[4];
  const float* W3  = (const float*)d_in[5];
  const float* B3  = (const float*)d_in[6];
  const float* W4  = (const float*)d_in[7];
  const float* B4  = (const float*)d_in[8];
  const float* fcw = (const float*)d_in[9];
  const float* fcb = (const float*)d_in[10];
  float* out = (float*)d_out;

  const int batch  = in_sizes[0] / (6 * 64);  // 131072
  const int blocks = batch / 16;              // one 16-batch tile per block
  hipLaunchKernelGGL(gcn_fused, dim3(blocks), dim3(256), 0, stream,
                     x, W1, B1, W2, B2, W3, B3, W4, B4, fcw, fcb, out);
}

// Round 4
// 88.063 us; speedup vs baseline: 1.8779x; 1.8779x over previous
//
#include <hip/hip_runtime.h>

typedef __attribute__((ext_vector_type(8))) _Float16 f16x8;
typedef __attribute__((ext_vector_type(2))) __fp16 fp16x2;
typedef __attribute__((ext_vector_type(4))) float f32x4;

union U8 { f16x8 v; fp16x2 p[4]; };

__device__ __forceinline__ f16x8 cvt8(f32x4 a, f32x4 b) {
  U8 u;
  u.p[0] = __builtin_amdgcn_cvt_pkrtz(a.x, a.y);
  u.p[1] = __builtin_amdgcn_cvt_pkrtz(a.z, a.w);
  u.p[2] = __builtin_amdgcn_cvt_pkrtz(b.x, b.y);
  u.p[3] = __builtin_amdgcn_cvt_pkrtz(b.z, b.w);
  return u.v;
}

__device__ __forceinline__ float dot4(f32x4 a, f32x4 b) {
  return a.x * b.x + a.y * b.y + a.z * b.z + a.w * b.w;
}

#define PAD 80

// Block = 16 batch rows. Wave w owns output-feature tile [16w,16w+16).
// Aggregation folded into MFMA via pre-scaled W fragments (Wa=ca*W, Wb=cb*W):
// acc[n] = bias + sum over contributing inputs m of (H_m * W_scaled).
__global__ __launch_bounds__(256, 8) void gcn_fused(
    const float* __restrict__ x,
    const float* __restrict__ W1, const float* __restrict__ B1,
    const float* __restrict__ W2, const float* __restrict__ B2,
    const float* __restrict__ W3, const float* __restrict__ B3,
    const float* __restrict__ W4, const float* __restrict__ B4,
    const float* __restrict__ fcw, const float* __restrict__ fcb,
    float* __restrict__ out)
{
  __shared__ __align__(16) _Float16 xs[6][16][PAD];  // h[node][batch][feat] (f16)
  __shared__ float pacc_s[6][16];                    // residual x . fcw partial dots
  __shared__ float ls[16][6];                        // final logits staging

  const int tid  = threadIdx.x;
  const int lane = tid & 63;
  const int w    = tid >> 6;    // wave id = output-feature tile
  const int c    = lane & 15;   // A-row (batch) / B-col (feature)
  const int q    = lane >> 4;   // k-group / C row-group
  const int b0   = blockIdx.x * 16;

  // consumers of input node m (includes self); -1 = unused
  const int CONS[6][4] = {{0,1,-1,-1},{0,1,2,-1},{0,1,2,3},{2,3,4,5},{3,4,5,-1},{4,5,-1,-1}};
  const float* Ws[4] = {W1, W2, W3, W4};
  const float* Bs[4] = {B1, B2, B3, B4};

  // ---- stage x -> xs (f16, coalesced) + residual partial dots ----
  {
    const float* xb = x + (size_t)b0 * 384;
#pragma unroll
    for (int r = 0; r < 3; ++r) {
      const int i = tid * 8 + r * 2048;          // flat elem in 16x6x64 tile
      const int b = i / 384;
      const int rem = i - b * 384;
      const int n = rem >> 6;
      const int f = rem & 63;
      f32x4 v0 = *(const f32x4*)(xb + i);
      f32x4 v1 = *(const f32x4*)(xb + i + 4);
      const float* fw = fcw + n * 64 + f;
      float p = dot4(v0, *(const f32x4*)fw) + dot4(v1, *(const f32x4*)(fw + 4));
      p += __shfl_xor(p, 1, 64);
      p += __shfl_xor(p, 2, 64);
      p += __shfl_xor(p, 4, 64);
      if ((tid & 7) == 0) pacc_s[n][b] = p;      // 8 threads cover one (b,n)
      *(f16x8*)&xs[n][b][f] = cvt8(v0, v1);
    }
  }
  __syncthreads();

  f32x4 acc[6];

#pragma unroll
  for (int l = 0; l < 4; ++l) {
    // scaled W fragments: wb = cb*W (neighbor), wa = ca*W (self)
    const float cbv = (l < 2) ? (1.f / 3.f) : 0.25f;
    const float* wp = Ws[l] + (w * 16 + c) * 64 + q * 8;
    f32x4 u0 = *(const f32x4*)wp        * cbv;
    f32x4 u1 = *(const f32x4*)(wp + 4)  * cbv;
    f32x4 u2 = *(const f32x4*)(wp + 32) * cbv;
    f32x4 u3 = *(const f32x4*)(wp + 36) * cbv;
    f16x8 wb0 = cvt8(u0, u1), wb1 = cvt8(u2, u3);
    f16x8 wa0, wa1;
    if (l < 2) { wa0 = wb0; wa1 = wb1; }           // ca == cb
    else       { wa0 = wb0 + wb0; wa1 = wb1 + wb1; } // ca == 2*cb
    const float bv = Bs[l][w * 16 + c];
    const f32x4 bc = {bv, bv, bv, bv};
#pragma unroll
    for (int n = 0; n < 6; ++n) acc[n] = bc;       // bias in accumulator init

    // stream inputs m; scatter into consumer accumulators via MFMA
#pragma unroll
    for (int m = 0; m < 6; ++m) {
      f16x8 a0 = *(const f16x8*)&xs[m][c][q * 8];
      f16x8 a1 = *(const f16x8*)&xs[m][c][q * 8 + 32];
#pragma unroll
      for (int j = 0; j < 4; ++j) {
        const int n = CONS[m][j];
        if (n >= 0) {
          acc[n] = __builtin_amdgcn_mfma_f32_16x16x32_f16(a0, (n == m) ? wa0 : wb0, acc[n], 0, 0, 0);
          acc[n] = __builtin_amdgcn_mfma_f32_16x16x32_f16(a1, (n == m) ? wa1 : wb1, acc[n], 0, 0, 0);
        }
      }
    }
    __syncthreads();  // all waves done reading xs for this layer
    // relu + writeback (C-frag: col = w*16+c, rows = 4q+e)
#pragma unroll
    for (int n = 0; n < 6; ++n)
#pragma unroll
      for (int e = 0; e < 4; ++e)
        xs[n][q * 4 + e][w * 16 + c] = (_Float16)fmaxf(acc[n][e], 0.f);
    __syncthreads();  // writes visible (next layer / epilogue)
  }

  // ---- epilogue: logits[b,n] = dot(h4[b,n,:], fcw[n,:]) + pacc + fcb, sigmoid ----
  const f32x4 z4 = {0.f, 0.f, 0.f, 0.f};
  for (int n = w; n < 6; n += 4) {   // nodes split across waves
    f16x8 a0 = *(const f16x8*)&xs[n][c][q * 8];
    f16x8 a1 = *(const f16x8*)&xs[n][c][q * 8 + 32];
    const float* fw = fcw + n * 64 + q * 8;
    // broadcast B-frag: every output column = fcw[n] -> each lane's C rows hold the dot
    f16x8 bf0 = cvt8(*(const f32x4*)fw,        *(const f32x4*)(fw + 4));
    f16x8 bf1 = cvt8(*(const f32x4*)(fw + 32), *(const f32x4*)(fw + 36));
    f32x4 sv = __builtin_amdgcn_mfma_f32_16x16x32_f16(a0, bf0, z4, 0, 0, 0);
    sv = __builtin_amdgcn_mfma_f32_16x16x32_f16(a1, bf1, sv, 0, 0, 0);
    if (c == 0) {
      const float fb = fcb[n];
#pragma unroll
      for (int e = 0; e < 4; ++e) {
        const float v = sv[e] + pacc_s[n][q * 4 + e] + fb;
        ls[q * 4 + e][n] = 1.f / (1.f + __expf(-v));
      }
    }
  }
  __syncthreads();
  if (tid < 96) out[(size_t)b0 * 6 + tid] = ((const float*)ls)[tid];
}

extern "C" void kernel_launch(void* const* d_in, const int* in_sizes, int n_in,
                              void* d_out, int out_size, void* d_ws, size_t ws_size,
                              hipStream_t stream) {
  const float* x   = (const float*)d_in[0];
  const float* W1  = (const float*)d_in[1];
  const float* B1  = (const float*)d_in[2];
  const float* W2  = (const float*)d_in[3];
  const float* B2  = (const float*)d_in[4];
  const float* W3  = (const float*)d_in[5];
  const float* B3  = (const float*)d_in[6];
  const float* W4  = (const float*)d_in[7];
  const float* B4  = (const float*)d_in[8];
  const float* fcw = (const float*)d_in[9];
  const float* fcb = (const float*)d_in[10];
  float* out = (float*)d_out;

  const int batch  = in_sizes[0] / (6 * 64);  // 131072
  const int blocks = batch / 16;
  hipLaunchKernelGGL(gcn_fused, dim3(blocks), dim3(256), 0, stream,
                     x, W1, B1, W2, B2, W3, B3, W4, B4, fcw, fcb, out);
}

// Round 5
// 77.589 us; speedup vs baseline: 2.1314x; 1.1350x over previous
//
#include <hip/hip_runtime.h>

typedef __attribute__((ext_vector_type(8))) _Float16 f16x8;
typedef __attribute__((ext_vector_type(4))) _Float16 f16x4;
typedef __attribute__((ext_vector_type(2))) __fp16 fp16x2;
typedef __attribute__((ext_vector_type(4))) float f32x4;

union U8 { f16x8 v; fp16x2 p[4]; };
union U4 { f16x4 v; fp16x2 p[2]; };

__device__ __forceinline__ f16x8 cvt8(f32x4 a, f32x4 b) {
  U8 u;
  u.p[0] = __builtin_amdgcn_cvt_pkrtz(a.x, a.y);
  u.p[1] = __builtin_amdgcn_cvt_pkrtz(a.z, a.w);
  u.p[2] = __builtin_amdgcn_cvt_pkrtz(b.x, b.y);
  u.p[3] = __builtin_amdgcn_cvt_pkrtz(b.z, b.w);
  return u.v;
}
__device__ __forceinline__ f16x4 cvt4(f32x4 a) {
  U4 u;
  u.p[0] = __builtin_amdgcn_cvt_pkrtz(a.x, a.y);
  u.p[1] = __builtin_amdgcn_cvt_pkrtz(a.z, a.w);
  return u.v;
}
__device__ __forceinline__ float dot4(f32x4 a, f32x4 b) {
  return a.x * b.x + a.y * b.y + a.z * b.z + a.w * b.w;
}

#define BT 32  // batch rows per block

// Flipped MFMA: A = W fragment (rows = out-feats), B = h fragment (cols = batch).
// C: row = 4q+e = out-feat (w*16+q*4+e), col = c = batch -> packed b64 writeback.
// xs layout: [node][batch][64 feats], 128B rows, 16B-slot XOR swizzle s^(batch&7).
__global__ __launch_bounds__(256, 4) void gcn_fused(
    const float* __restrict__ x,
    const float* __restrict__ W1, const float* __restrict__ B1,
    const float* __restrict__ W2, const float* __restrict__ B2,
    const float* __restrict__ W3, const float* __restrict__ B3,
    const float* __restrict__ W4, const float* __restrict__ B4,
    const float* __restrict__ fcw, const float* __restrict__ fcb,
    float* __restrict__ out)
{
  __shared__ __align__(16) _Float16 xs[6 * BT * 64];
  __shared__ float pacc_s[6][BT];
  __shared__ float ls[BT][6];

  const int tid  = threadIdx.x;
  const int lane = tid & 63;
  const int w    = tid >> 6;    // wave id = out-feature tile [16w, 16w+16)
  const int c    = lane & 15;   // A-row(out-feat local)/B-col(batch)
  const int q    = lane >> 4;   // k-group / C row-group
  const int b0   = blockIdx.x * BT;

  const int CONS[6][4] = {{0,1,-1,-1},{0,1,2,-1},{0,1,2,3},{2,3,4,5},{3,4,5,-1},{4,5,-1,-1}};
  const float* Ws[4] = {W1, W2, W3, W4};
  const float* Bs[4] = {B1, B2, B3, B4};

  // ---- stage x -> xs (f16, swizzled) + residual fc-dot partials ----
  {
    const float* xb = x + (size_t)b0 * 384;
#pragma unroll
    for (int r = 0; r < 6; ++r) {
      const int i = tid * 8 + r * 2048;     // flat elem in 32x6x64 tile
      const int b = i / 384;
      const int rem = i - b * 384;
      const int n = rem >> 6;
      const int f = rem & 63;
      f32x4 v0 = *(const f32x4*)(xb + i);
      f32x4 v1 = *(const f32x4*)(xb + i + 4);
      const float* fw = fcw + n * 64 + f;
      float p = dot4(v0, *(const f32x4*)fw) + dot4(v1, *(const f32x4*)(fw + 4));
      p += __shfl_xor(p, 1, 64);
      p += __shfl_xor(p, 2, 64);
      p += __shfl_xor(p, 4, 64);
      if ((tid & 7) == 0) pacc_s[n][b] = p;
      const int slot = (f >> 3) ^ (b & 7);
      *(f16x8*)&xs[(n * BT + b) * 64 + slot * 8] = cvt8(v0, v1);
    }
  }
  __syncthreads();

  f32x4 acc[2][6];
  const int s1 = (q ^ (c & 7)) * 8;         // read slot, k = q*8..
  const int s2 = ((q + 4) ^ (c & 7)) * 8;   // read slot, k = 32+q*8..
  const int wsl = ((w * 2 + (q >> 1)) ^ (c & 7)) * 8 + (q & 1) * 4;  // write slot

#pragma unroll
  for (int l = 0; l < 4; ++l) {
    // scaled W A-fragments: wb = cb*W (neighbor), wa = ca*W (self)
    const float cbv = (l < 2) ? (1.f / 3.f) : 0.25f;
    const float* wp = Ws[l] + (w * 16 + c) * 64 + q * 8;
    f32x4 u0 = *(const f32x4*)wp        * cbv;
    f32x4 u1 = *(const f32x4*)(wp + 4)  * cbv;
    f32x4 u2 = *(const f32x4*)(wp + 32) * cbv;
    f32x4 u3 = *(const f32x4*)(wp + 36) * cbv;
    f16x8 wb0 = cvt8(u0, u1), wb1 = cvt8(u2, u3);
    f16x8 wa0, wa1;
    if (l < 2) { wa0 = wb0; wa1 = wb1; }
    else       { wa0 = wb0 + wb0; wa1 = wb1 + wb1; }
    const f32x4 bval = *(const f32x4*)(Bs[l] + w * 16 + q * 4);  // bias rows 4q+e
#pragma unroll
    for (int hh = 0; hh < 2; ++hh)
#pragma unroll
      for (int n = 0; n < 6; ++n) acc[hh][n] = bval;

#pragma unroll
    for (int m = 0; m < 6; ++m) {
#pragma unroll
      for (int hh = 0; hh < 2; ++hh) {
        const int row = (m * BT + hh * 16 + c) * 64;
        f16x8 a0 = *(const f16x8*)&xs[row + s1];
        f16x8 a1 = *(const f16x8*)&xs[row + s2];
#pragma unroll
        for (int j = 0; j < 4; ++j) {
          const int n = CONS[m][j];
          if (n >= 0) {
            acc[hh][n] = __builtin_amdgcn_mfma_f32_16x16x32_f16((n == m) ? wa0 : wb0, a0, acc[hh][n], 0, 0, 0);
            acc[hh][n] = __builtin_amdgcn_mfma_f32_16x16x32_f16((n == m) ? wa1 : wb1, a1, acc[hh][n], 0, 0, 0);
          }
        }
      }
    }
    __syncthreads();  // all waves done reading xs for this layer
    // relu + packed b64 writeback: feats w*16+q*4+{0..3} of batch row
#pragma unroll
    for (int hh = 0; hh < 2; ++hh) {
      const int brow = hh * 16 + c;
#pragma unroll
      for (int n = 0; n < 6; ++n) {
        f32x4 r;
#pragma unroll
        for (int e = 0; e < 4; ++e) r[e] = fmaxf(acc[hh][n][e], 0.f);
        *(f16x4*)&xs[(n * BT + brow) * 64 + wsl] = cvt4(r);
      }
    }
    __syncthreads();  // writes visible (next layer / epilogue)
  }

  // ---- epilogue: broadcast-fcw A-frag; all C rows = dot(h4[b,n,:], fcw[n,:]) ----
  const f32x4 z4 = {0.f, 0.f, 0.f, 0.f};
#pragma unroll
  for (int u = w; u < 12; u += 4) {       // 12 (node, half) units over 4 waves
    const int n = u % 6;
    const int hh = u / 6;
    const int row = (n * BT + hh * 16 + c) * 64;
    f16x8 hb0 = *(const f16x8*)&xs[row + s1];
    f16x8 hb1 = *(const f16x8*)&xs[row + s2];
    const float* fw = fcw + n * 64 + q * 8;
    f16x8 fa0 = cvt8(*(const f32x4*)fw,        *(const f32x4*)(fw + 4));
    f16x8 fa1 = cvt8(*(const f32x4*)(fw + 32), *(const f32x4*)(fw + 36));
    f32x4 sv = __builtin_amdgcn_mfma_f32_16x16x32_f16(fa0, hb0, z4, 0, 0, 0);
    sv = __builtin_amdgcn_mfma_f32_16x16x32_f16(fa1, hb1, sv, 0, 0, 0);
    if (q == 0) {
      const float v = sv[0] + pacc_s[n][hh * 16 + c] + fcb[n];
      ls[hh * 16 + c][n] = 1.f / (1.f + __expf(-v));
    }
  }
  __syncthreads();
  if (tid < 192) out[(size_t)b0 * 6 + tid] = ((const float*)ls)[tid];
}

extern "C" void kernel_launch(void* const* d_in, const int* in_sizes, int n_in,
                              void* d_out, int out_size, void* d_ws, size_t ws_size,
                              hipStream_t stream) {
  const float* x   = (const float*)d_in[0];
  const float* W1  = (const float*)d_in[1];
  const float* B1  = (const float*)d_in[2];
  const float* W2  = (const float*)d_in[3];
  const float* B2  = (const float*)d_in[4];
  const float* W3  = (const float*)d_in[5];
  const float* B3  = (const float*)d_in[6];
  const float* W4  = (const float*)d_in[7];
  const float* B4  = (const float*)d_in[8];
  const float* fcw = (const float*)d_in[9];
  const float* fcb = (const float*)d_in[10];
  float* out = (float*)d_out;

  const int batch  = in_sizes[0] / (6 * 64);  // 131072
  const int blocks = batch / BT;
  hipLaunchKernelGGL(gcn_fused, dim3(blocks), dim3(256), 0, stream,
                     x, W1, B1, W2, B2, W3, B3, W4, B4, fcw, fcb, out);
}